// Round 1
// baseline (359.244 us; speedup 1.0000x reference)
//
#include <hip/hip_runtime.h>

#define D 128

// ---------------- CSR build ----------------

__global__ void k_count(const int* __restrict__ node_idx, const int* __restrict__ hedge_idx,
                        int ni, int* __restrict__ cnt_v, int* __restrict__ cnt_e){
  int i = blockIdx.x * 256 + threadIdx.x;
  if (i < ni){
    atomicAdd(&cnt_v[node_idx[i]], 1);
    atomicAdd(&cnt_e[hedge_idx[i]], 1);
  }
}

// block b sums cnt[b*1024 .. b*1024+1023]
__global__ void k_scan_partial(const int* __restrict__ cnt, int n, int* __restrict__ bsum){
  __shared__ int s[256];
  int b = blockIdx.x, t = threadIdx.x;
  int base = b * 1024;
  int acc = 0;
  for (int j = t; j < 1024; j += 256){
    int idx = base + j;
    if (idx < n) acc += cnt[idx];
  }
  s[t] = acc; __syncthreads();
  for (int o = 128; o > 0; o >>= 1){
    if (t < o) s[t] += s[t + o];
    __syncthreads();
  }
  if (t == 0) bsum[b] = s[0];
}

// single block: in-place exclusive scan of bsum[0..nb)
__global__ void k_scan_bsums(int* __restrict__ bsum, int nb){
  __shared__ int s[256];
  int t = threadIdx.x;
  int runbase = 0;
  for (int base = 0; base < nb; base += 256){
    int v = (base + t < nb) ? bsum[base + t] : 0;
    s[t] = v;
    __syncthreads();
    for (int o = 1; o < 256; o <<= 1){
      int x = (t >= o) ? s[t - o] : 0;
      __syncthreads();
      s[t] += x;
      __syncthreads();
    }
    int total = s[255];
    if (base + t < nb) bsum[base + t] = runbase + (s[t] - v);  // exclusive
    __syncthreads();
    runbase += total;
  }
}

// block b: exclusive scan of its 1024 chunk + bsum[b] base -> off[]
__global__ void k_scan_final(const int* __restrict__ cnt, int n,
                             const int* __restrict__ bsum, int* __restrict__ off){
  __shared__ int s[256];
  int b = blockIdx.x, t = threadIdx.x;
  int base = b * 1024 + t * 4;
  int v0 = (base + 0 < n) ? cnt[base + 0] : 0;
  int v1 = (base + 1 < n) ? cnt[base + 1] : 0;
  int v2 = (base + 2 < n) ? cnt[base + 2] : 0;
  int v3 = (base + 3 < n) ? cnt[base + 3] : 0;
  int lsum = v0 + v1 + v2 + v3;
  s[t] = lsum; __syncthreads();
  for (int o = 1; o < 256; o <<= 1){
    int x = (t >= o) ? s[t - o] : 0;
    __syncthreads();
    s[t] += x;
    __syncthreads();
  }
  int excl = s[t] - lsum + bsum[b];
  if (base + 0 < n) off[base + 0] = excl;
  if (base + 1 < n) off[base + 1] = excl + v0;
  if (base + 2 < n) off[base + 2] = excl + v0 + v1;
  if (base + 3 < n) off[base + 3] = excl + v0 + v1 + v2;
}

__global__ void k_fill(const int* __restrict__ node_idx, const int* __restrict__ hedge_idx,
                       int ni, const int* __restrict__ off_v, const int* __restrict__ off_e,
                       int* __restrict__ cur_v, int* __restrict__ cur_e,
                       int* __restrict__ vlist_e, int* __restrict__ elist_v){
  int i = blockIdx.x * 256 + threadIdx.x;
  if (i < ni){
    int v = node_idx[i];
    int e = hedge_idx[i];
    int pe = off_e[e] + atomicAdd(&cur_e[e], 1);
    elist_v[pe] = v;              // for hedge segments: which vertex row to gather
    int pv = off_v[v] + atomicAdd(&cur_v[v], 1);
    vlist_e[pv] = e;              // for vertex segments: which edge row to gather
  }
}

// ---------------- weight merge: Wc = Wve @ W1, bc = Wve@b1 + bve ----------------

__global__ void k_wmerge(const float* __restrict__ W1, const float* __restrict__ Wve,
                         const float* __restrict__ b1, const float* __restrict__ bve,
                         float* __restrict__ Wc, float* __restrict__ bc){
  int r = blockIdx.x;   // 0..127
  int c = threadIdx.x;  // 0..127
  float acc = 0.f;
  for (int k = 0; k < D; ++k)
    acc += Wve[r * D + k] * W1[k * D + c];
  Wc[r * D + c] = acc;
  if (c == 0){
    float s = 0.f;
    for (int k = 0; k < D; ++k) s += Wve[r * D + k] * b1[k];
    bc[r] = s + bve[r];
  }
}

// ---------------- GEMM: out[M x 128] = A[M x 128] @ W.T + bias ----------------
// W is [128 x 128] row-major, W[c][k]. Block tile: 32 rows x 128 cols.

__global__ __launch_bounds__(256, 2)
void k_gemm(const float* __restrict__ A, const float* __restrict__ W,
            const float* __restrict__ bias, float* __restrict__ out, int M){
  __shared__ float WT[D * D];       // WT[k*128 + c] = W[c][k]   (64 KB)
  __shared__ float rowT[D * 32];    // rowT[k*32 + r] = A[row0+r][k] (16 KB)

  const int t = threadIdx.x;
  // Stage WT (once per block): thread handles c4=(t&31)*4, k = (t>>5) + p*8
  {
    int c4 = (t & 31) * 4;
    int k0 = t >> 5;
#pragma unroll
    for (int p = 0; p < 16; ++p){
      int k = k0 + p * 8;
      float4 v;
      v.x = W[(c4 + 0) * D + k];
      v.y = W[(c4 + 1) * D + k];
      v.z = W[(c4 + 2) * D + k];
      v.w = W[(c4 + 3) * D + k];
      *(float4*)&WT[k * D + c4] = v;
    }
  }

  const int tc4 = (t & 31) * 4;
  const int tr4 = (t >> 5) * 4;
  const float4 b4 = *(const float4*)&bias[tc4];

  const int ntile = (M + 31) >> 5;
  for (int tile = blockIdx.x; tile < ntile; tile += gridDim.x){
    int row0 = tile * 32;
    __syncthreads();   // protect rowT (previous iter readers) + WT first-use
    // Stage rowT: lane rL = t&31 owns row rL; kc walks the 128 k's
    {
      int rL = t & 31;
      int r = row0 + rL;
#pragma unroll
      for (int p = 0; p < 4; ++p){
        int kc = ((t >> 5) + p * 8) * 4;
        float4 v;
        if (r < M) v = *(const float4*)&A[(size_t)r * D + kc];
        else { v.x = v.y = v.z = v.w = 0.f; }
        rowT[(kc + 0) * 32 + rL] = v.x;
        rowT[(kc + 1) * 32 + rL] = v.y;
        rowT[(kc + 2) * 32 + rL] = v.z;
        rowT[(kc + 3) * 32 + rL] = v.w;
      }
    }
    __syncthreads();

    float4 acc0 = {0,0,0,0}, acc1 = {0,0,0,0}, acc2 = {0,0,0,0}, acc3 = {0,0,0,0};
#pragma unroll 16
    for (int k = 0; k < D; ++k){
      const float4 a = *(const float4*)&rowT[k * 32 + tr4];
      const float4 w = *(const float4*)&WT[k * D + tc4];
      acc0.x += a.x * w.x; acc0.y += a.x * w.y; acc0.z += a.x * w.z; acc0.w += a.x * w.w;
      acc1.x += a.y * w.x; acc1.y += a.y * w.y; acc1.z += a.y * w.z; acc1.w += a.y * w.w;
      acc2.x += a.z * w.x; acc2.y += a.z * w.y; acc2.z += a.z * w.z; acc2.w += a.z * w.w;
      acc3.x += a.w * w.x; acc3.y += a.w * w.y; acc3.z += a.w * w.z; acc3.w += a.w * w.w;
    }

    int orow = row0 + tr4;
    float4 o;
    if (orow + 0 < M){ o.x=acc0.x+b4.x; o.y=acc0.y+b4.y; o.z=acc0.z+b4.z; o.w=acc0.w+b4.w;
                       *(float4*)&out[(size_t)(orow+0)*D + tc4] = o; }
    if (orow + 1 < M){ o.x=acc1.x+b4.x; o.y=acc1.y+b4.y; o.z=acc1.z+b4.z; o.w=acc1.w+b4.w;
                       *(float4*)&out[(size_t)(orow+1)*D + tc4] = o; }
    if (orow + 2 < M){ o.x=acc2.x+b4.x; o.y=acc2.y+b4.y; o.z=acc2.z+b4.z; o.w=acc2.w+b4.w;
                       *(float4*)&out[(size_t)(orow+2)*D + tc4] = o; }
    if (orow + 3 < M){ o.x=acc3.x+b4.x; o.y=acc3.y+b4.y; o.z=acc3.z+b4.z; o.w=acc3.w+b4.w;
                       *(float4*)&out[(size_t)(orow+3)*D + tc4] = o; }
  }
}

// ---------------- weighted segment gather-sum ----------------
// One wave per segment: dst[seg] = sum_j (wnum[list[j]] / dsum[seg]) * src[list[j]]

__global__ void k_scatter(const float* __restrict__ src,
                          const int* __restrict__ off, const int* __restrict__ cnt,
                          const int* __restrict__ list,
                          const float* __restrict__ wnum, const float* __restrict__ dsum,
                          float* __restrict__ dst, int nseg){
  int gw = (blockIdx.x * 256 + threadIdx.x) >> 6;
  if (gw >= nseg) return;
  int lane = threadIdx.x & 63;
  int s = off[gw], n = cnt[gw];
  float inv = 1.0f / dsum[gw];
  float ax = 0.f, ay = 0.f;
  int j = 0;
  for (; j + 2 <= n; j += 2){
    int r0 = list[s + j];
    int r1 = list[s + j + 1];
    float w0 = wnum[r0] * inv;
    float w1 = wnum[r1] * inv;
    float2 x0 = *(const float2*)&src[(size_t)r0 * D + lane * 2];
    float2 x1 = *(const float2*)&src[(size_t)r1 * D + lane * 2];
    ax += w0 * x0.x; ay += w0 * x0.y;
    ax += w1 * x1.x; ay += w1 * x1.y;
  }
  if (j < n){
    int r0 = list[s + j];
    float w0 = wnum[r0] * inv;
    float2 x0 = *(const float2*)&src[(size_t)r0 * D + lane * 2];
    ax += w0 * x0.x; ay += w0 * x0.y;
  }
  float2 o; o.x = ax; o.y = ay;
  *(float2*)&dst[(size_t)gw * D + lane * 2] = o;
}

// ---------------- host ----------------

static inline int cdiv(int a, int b){ return (a + b - 1) / b; }

extern "C" void kernel_launch(void* const* d_in, const int* in_sizes, int n_in,
                              void* d_out, int out_size, void* d_ws, size_t ws_size,
                              hipStream_t stream){
  const float* vfeat        = (const float*)d_in[0];
  const float* v_reg_weight = (const float*)d_in[2];
  const float* v_reg_sum    = (const float*)d_in[3];
  const float* e_reg_weight = (const float*)d_in[4];
  const float* e_reg_sum    = (const float*)d_in[5];
  const int*   node_idx     = (const int*)d_in[6];
  const int*   hedge_idx    = (const int*)d_in[7];
  const float* W1  = (const float*)d_in[8];
  const float* b1  = (const float*)d_in[9];
  const float* Wve = (const float*)d_in[10];
  const float* bve = (const float*)d_in[11];
  const float* Wev = (const float*)d_in[12];
  const float* bev = (const float*)d_in[13];

  const int NV = in_sizes[2];
  const int NE = in_sizes[4];
  const int NI = in_sizes[6];

  char* p = (char*)d_ws;
  auto alloc = [&](size_t nbytes) -> void* {
    void* q = (void*)p;
    p += (nbytes + 255) & ~(size_t)255;
    return q;
  };

  char* zstart = p;
  int* cnt_v = (int*)alloc((size_t)NV * 4);
  int* cnt_e = (int*)alloc((size_t)NE * 4);
  int* cur_v = (int*)alloc((size_t)NV * 4);
  int* cur_e = (int*)alloc((size_t)NE * 4);
  size_t zbytes = (size_t)(p - zstart);

  int* off_v  = (int*)alloc((size_t)NV * 4);
  int* off_e  = (int*)alloc((size_t)NE * 4);
  int* bsum_v = (int*)alloc(1024 * 4);
  int* bsum_e = (int*)alloc(1024 * 4);
  int* vlist_e = (int*)alloc((size_t)NI * 4);   // per vertex-slot: edge id
  int* elist_v = (int*)alloc((size_t)NI * 4);   // per edge-slot: vertex id
  float* Wc     = (float*)alloc((size_t)D * D * 4);
  float* bc     = (float*)alloc((size_t)D * 4);
  float* feat_e = (float*)alloc((size_t)NE * D * 4);
  float* Wh_e   = (float*)alloc((size_t)NE * D * 4);

  float* Wh_n = (float*)d_out;  // reuse output buffer as Wh_n scratch (fully overwritten later)

  hipMemsetAsync(zstart, 0, zbytes, stream);

  k_count<<<cdiv(NI, 256), 256, 0, stream>>>(node_idx, hedge_idx, NI, cnt_v, cnt_e);

  int nbe = cdiv(NE, 1024), nbv = cdiv(NV, 1024);
  k_scan_partial<<<nbe, 256, 0, stream>>>(cnt_e, NE, bsum_e);
  k_scan_bsums<<<1, 256, 0, stream>>>(bsum_e, nbe);
  k_scan_final<<<nbe, 256, 0, stream>>>(cnt_e, NE, bsum_e, off_e);
  k_scan_partial<<<nbv, 256, 0, stream>>>(cnt_v, NV, bsum_v);
  k_scan_bsums<<<1, 256, 0, stream>>>(bsum_v, nbv);
  k_scan_final<<<nbv, 256, 0, stream>>>(cnt_v, NV, bsum_v, off_v);

  k_fill<<<cdiv(NI, 256), 256, 0, stream>>>(node_idx, hedge_idx, NI, off_v, off_e,
                                            cur_v, cur_e, vlist_e, elist_v);

  k_wmerge<<<D, D, 0, stream>>>(W1, Wve, b1, bve, Wc, bc);

  int g1 = cdiv(NV, 32); if (g1 > 512) g1 = 512;
  k_gemm<<<g1, 256, 0, stream>>>(vfeat, Wc, bc, Wh_n, NV);

  k_scatter<<<cdiv(NE * 64, 256), 256, 0, stream>>>(Wh_n, off_e, cnt_e, elist_v,
                                                    v_reg_weight, e_reg_sum, feat_e, NE);

  int g2 = cdiv(NE, 32); if (g2 > 512) g2 = 512;
  k_gemm<<<g2, 256, 0, stream>>>(feat_e, Wev, bev, Wh_e, NE);

  k_scatter<<<cdiv(NV * 64, 256), 256, 0, stream>>>(Wh_e, off_v, cnt_v, vlist_e,
                                                    e_reg_weight, v_reg_sum, (float*)d_out, NV);
}

// Round 2
// 285.809 us; speedup vs baseline: 1.2569x; 1.2569x over previous
//
#include <hip/hip_runtime.h>

#define D 128

typedef unsigned short ushort_t;

static __device__ __forceinline__ unsigned short f2bf(float f){
  unsigned int b = __float_as_uint(f);
  unsigned int r = (b + 0x7FFFu + ((b >> 16) & 1u)) >> 16;
  return (unsigned short)r;
}
static __device__ __forceinline__ float bf2f(unsigned short u){
  return __uint_as_float(((unsigned int)u) << 16);
}

// ---------------- CSR build ----------------

__global__ void k_count(const int* __restrict__ node_idx, const int* __restrict__ hedge_idx,
                        int ni, int* __restrict__ cnt_v, int* __restrict__ cnt_e,
                        int* __restrict__ rank_v, int* __restrict__ rank_e){
  int i = blockIdx.x * 256 + threadIdx.x;
  if (i < ni){
    rank_v[i] = atomicAdd(&cnt_v[node_idx[i]], 1);
    rank_e[i] = atomicAdd(&cnt_e[hedge_idx[i]], 1);
  }
}

// block b sums cnt[b*1024 .. b*1024+1023]
__global__ void k_scan_partial(const int* __restrict__ cnt, int n, int* __restrict__ bsum){
  __shared__ int s[256];
  int b = blockIdx.x, t = threadIdx.x;
  int base = b * 1024;
  int acc = 0;
  for (int j = t; j < 1024; j += 256){
    int idx = base + j;
    if (idx < n) acc += cnt[idx];
  }
  s[t] = acc; __syncthreads();
  for (int o = 128; o > 0; o >>= 1){
    if (t < o) s[t] += s[t + o];
    __syncthreads();
  }
  if (t == 0) bsum[b] = s[0];
}

// single block: in-place exclusive scan of bsum[0..nb)
__global__ void k_scan_bsums(int* __restrict__ bsum, int nb){
  __shared__ int s[256];
  int t = threadIdx.x;
  int runbase = 0;
  for (int base = 0; base < nb; base += 256){
    int v = (base + t < nb) ? bsum[base + t] : 0;
    s[t] = v;
    __syncthreads();
    for (int o = 1; o < 256; o <<= 1){
      int x = (t >= o) ? s[t - o] : 0;
      __syncthreads();
      s[t] += x;
      __syncthreads();
    }
    int total = s[255];
    if (base + t < nb) bsum[base + t] = runbase + (s[t] - v);  // exclusive
    __syncthreads();
    runbase += total;
  }
}

// block b: exclusive scan of its 1024 chunk + bsum[b] base -> off[]
__global__ void k_scan_final(const int* __restrict__ cnt, int n,
                             const int* __restrict__ bsum, int* __restrict__ off){
  __shared__ int s[256];
  int b = blockIdx.x, t = threadIdx.x;
  int base = b * 1024 + t * 4;
  int v0 = (base + 0 < n) ? cnt[base + 0] : 0;
  int v1 = (base + 1 < n) ? cnt[base + 1] : 0;
  int v2 = (base + 2 < n) ? cnt[base + 2] : 0;
  int v3 = (base + 3 < n) ? cnt[base + 3] : 0;
  int lsum = v0 + v1 + v2 + v3;
  s[t] = lsum; __syncthreads();
  for (int o = 1; o < 256; o <<= 1){
    int x = (t >= o) ? s[t - o] : 0;
    __syncthreads();
    s[t] += x;
    __syncthreads();
  }
  int excl = s[t] - lsum + bsum[b];
  if (base + 0 < n) off[base + 0] = excl;
  if (base + 1 < n) off[base + 1] = excl + v0;
  if (base + 2 < n) off[base + 2] = excl + v0 + v1;
  if (base + 3 < n) off[base + 3] = excl + v0 + v1 + v2;
}

// pure scatter-store fill (no atomics; ranks precomputed)
__global__ void k_fill2(const int* __restrict__ node_idx, const int* __restrict__ hedge_idx,
                        const int* __restrict__ rank_v, const int* __restrict__ rank_e,
                        int ni, const int* __restrict__ off_v, const int* __restrict__ off_e,
                        int* __restrict__ vlist_e, int* __restrict__ elist_v){
  int i = blockIdx.x * 256 + threadIdx.x;
  if (i < ni){
    int v = node_idx[i];
    int e = hedge_idx[i];
    int pe = off_e[e] + rank_e[i];
    __builtin_nontemporal_store(v, &elist_v[pe]);   // grouped by hedge: vertex id
    int pv = off_v[v] + rank_v[i];
    __builtin_nontemporal_store(e, &vlist_e[pv]);   // grouped by vertex: edge id
  }
}

// ---------------- weight merge: Wc = Wve @ W1, bc = Wve@b1 + bve ----------------

__global__ void k_wmerge(const float* __restrict__ W1, const float* __restrict__ Wve,
                         const float* __restrict__ b1, const float* __restrict__ bve,
                         float* __restrict__ Wc, float* __restrict__ bc){
  int r = blockIdx.x;   // 0..127
  int c = threadIdx.x;  // 0..127
  float acc = 0.f;
  for (int k = 0; k < D; ++k)
    acc += Wve[r * D + k] * W1[k * D + c];
  Wc[r * D + c] = acc;
  if (c == 0){
    float s = 0.f;
    for (int k = 0; k < D; ++k) s += Wve[r * D + k] * b1[k];
    bc[r] = s + bve[r];
  }
}

// ---------------- GEMM: out[M x 128] = A[M x 128] @ W.T + bias ----------------
// W is [128 x 128] row-major, W[c][k]. Block tile: 32 rows x 128 cols.
// BF16OUT=true stores the result rounded to bf16 (for gather-side traffic).

template<bool BF16OUT>
__global__ __launch_bounds__(256, 2)
void k_gemm(const float* __restrict__ A, const float* __restrict__ W,
            const float* __restrict__ bias, void* __restrict__ out_, int M){
  __shared__ float WT[D * D];       // WT[k*128 + c] = W[c][k]   (64 KB)
  __shared__ float rowT[D * 32];    // rowT[k*32 + r] = A[row0+r][k] (16 KB)

  const int t = threadIdx.x;
  {
    int c4 = (t & 31) * 4;
    int k0 = t >> 5;
#pragma unroll
    for (int p = 0; p < 16; ++p){
      int k = k0 + p * 8;
      float4 v;
      v.x = W[(c4 + 0) * D + k];
      v.y = W[(c4 + 1) * D + k];
      v.z = W[(c4 + 2) * D + k];
      v.w = W[(c4 + 3) * D + k];
      *(float4*)&WT[k * D + c4] = v;
    }
  }

  const int tc4 = (t & 31) * 4;
  const int tr4 = (t >> 5) * 4;
  const float4 b4 = *(const float4*)&bias[tc4];

  const int ntile = (M + 31) >> 5;
  for (int tile = blockIdx.x; tile < ntile; tile += gridDim.x){
    int row0 = tile * 32;
    __syncthreads();   // protect rowT (previous iter readers) + WT first-use
    {
      int rL = t & 31;
      int r = row0 + rL;
#pragma unroll
      for (int p = 0; p < 4; ++p){
        int kc = ((t >> 5) + p * 8) * 4;
        float4 v;
        if (r < M) v = *(const float4*)&A[(size_t)r * D + kc];
        else { v.x = v.y = v.z = v.w = 0.f; }
        rowT[(kc + 0) * 32 + rL] = v.x;
        rowT[(kc + 1) * 32 + rL] = v.y;
        rowT[(kc + 2) * 32 + rL] = v.z;
        rowT[(kc + 3) * 32 + rL] = v.w;
      }
    }
    __syncthreads();

    float4 acc0 = {0,0,0,0}, acc1 = {0,0,0,0}, acc2 = {0,0,0,0}, acc3 = {0,0,0,0};
#pragma unroll 16
    for (int k = 0; k < D; ++k){
      const float4 a = *(const float4*)&rowT[k * 32 + tr4];
      const float4 w = *(const float4*)&WT[k * D + tc4];
      acc0.x += a.x * w.x; acc0.y += a.x * w.y; acc0.z += a.x * w.z; acc0.w += a.x * w.w;
      acc1.x += a.y * w.x; acc1.y += a.y * w.y; acc1.z += a.y * w.z; acc1.w += a.y * w.w;
      acc2.x += a.z * w.x; acc2.y += a.z * w.y; acc2.z += a.z * w.z; acc2.w += a.z * w.w;
      acc3.x += a.w * w.x; acc3.y += a.w * w.y; acc3.z += a.w * w.z; acc3.w += a.w * w.w;
    }

    int orow = row0 + tr4;
    float4 accs[4] = {acc0, acc1, acc2, acc3};
#pragma unroll
    for (int q = 0; q < 4; ++q){
      if (orow + q < M){
        float4 o;
        o.x = accs[q].x + b4.x; o.y = accs[q].y + b4.y;
        o.z = accs[q].z + b4.z; o.w = accs[q].w + b4.w;
        if (BF16OUT){
          ushort4 h;
          h.x = f2bf(o.x); h.y = f2bf(o.y); h.z = f2bf(o.z); h.w = f2bf(o.w);
          *(ushort4*)((ushort_t*)out_ + (size_t)(orow + q) * D + tc4) = h;
        } else {
          *(float4*)((float*)out_ + (size_t)(orow + q) * D + tc4) = o;
        }
      }
    }
  }
}

// ---------------- weighted segment gather-sum (bf16 source rows) ----------------
// One wave per segment: dst[seg] = sum_j (wnum[list[j]] / dsum[seg]) * src[list[j]]

__global__ void k_scatter(const ushort_t* __restrict__ src,
                          const int* __restrict__ off, const int* __restrict__ cnt,
                          const int* __restrict__ list,
                          const float* __restrict__ wnum, const float* __restrict__ dsum,
                          float* __restrict__ dst, int nseg){
  int gw = (blockIdx.x * 256 + threadIdx.x) >> 6;
  if (gw >= nseg) return;
  int lane = threadIdx.x & 63;
  int s = __builtin_amdgcn_readfirstlane(off[gw]);
  int n = __builtin_amdgcn_readfirstlane(cnt[gw]);
  float inv = 1.0f / dsum[gw];
  float ax = 0.f, ay = 0.f;
  int j = 0;
  for (; j + 2 <= n; j += 2){
    int r0 = __builtin_amdgcn_readfirstlane(list[s + j]);
    int r1 = __builtin_amdgcn_readfirstlane(list[s + j + 1]);
    float w0 = wnum[r0] * inv;
    float w1 = wnum[r1] * inv;
    ushort2 x0 = *(const ushort2*)&src[(size_t)r0 * D + lane * 2];
    ushort2 x1 = *(const ushort2*)&src[(size_t)r1 * D + lane * 2];
    ax += w0 * bf2f(x0.x); ay += w0 * bf2f(x0.y);
    ax += w1 * bf2f(x1.x); ay += w1 * bf2f(x1.y);
  }
  if (j < n){
    int r0 = __builtin_amdgcn_readfirstlane(list[s + j]);
    float w0 = wnum[r0] * inv;
    ushort2 x0 = *(const ushort2*)&src[(size_t)r0 * D + lane * 2];
    ax += w0 * bf2f(x0.x); ay += w0 * bf2f(x0.y);
  }
  float2 o; o.x = ax; o.y = ay;
  *(float2*)&dst[(size_t)gw * D + lane * 2] = o;
}

// ---------------- host ----------------

static inline int cdiv(int a, int b){ return (a + b - 1) / b; }

extern "C" void kernel_launch(void* const* d_in, const int* in_sizes, int n_in,
                              void* d_out, int out_size, void* d_ws, size_t ws_size,
                              hipStream_t stream){
  const float* vfeat        = (const float*)d_in[0];
  const float* v_reg_weight = (const float*)d_in[2];
  const float* v_reg_sum    = (const float*)d_in[3];
  const float* e_reg_weight = (const float*)d_in[4];
  const float* e_reg_sum    = (const float*)d_in[5];
  const int*   node_idx     = (const int*)d_in[6];
  const int*   hedge_idx    = (const int*)d_in[7];
  const float* W1  = (const float*)d_in[8];
  const float* b1  = (const float*)d_in[9];
  const float* Wve = (const float*)d_in[10];
  const float* bve = (const float*)d_in[11];
  const float* Wev = (const float*)d_in[12];
  const float* bev = (const float*)d_in[13];

  const int NV = in_sizes[2];
  const int NE = in_sizes[4];
  const int NI = in_sizes[6];

  char* p = (char*)d_ws;
  auto alloc = [&](size_t nbytes) -> void* {
    void* q = (void*)p;
    p += (nbytes + 255) & ~(size_t)255;
    return q;
  };

  char* zstart = p;
  int* cnt_v = (int*)alloc((size_t)NV * 4);
  int* cnt_e = (int*)alloc((size_t)NE * 4);
  size_t zbytes = (size_t)(p - zstart);

  int* off_v  = (int*)alloc((size_t)NV * 4);
  int* off_e  = (int*)alloc((size_t)NE * 4);
  int* bsum_v = (int*)alloc(1024 * 4);
  int* bsum_e = (int*)alloc(1024 * 4);
  int* rank_v = (int*)alloc((size_t)NI * 4);
  int* rank_e = (int*)alloc((size_t)NI * 4);
  int* vlist_e = (int*)alloc((size_t)NI * 4);   // per vertex-slot: edge id
  int* elist_v = (int*)alloc((size_t)NI * 4);   // per edge-slot: vertex id
  float* Wc     = (float*)alloc((size_t)D * D * 4);
  float* bc     = (float*)alloc((size_t)D * 4);
  float* feat_e = (float*)alloc((size_t)NE * D * 4);
  ushort_t* Wh_e = (ushort_t*)alloc((size_t)NE * D * 2);

  // Wh_n (bf16) lives in d_out's storage; d_out is fully overwritten by the
  // final scatter, which doesn't read Wh_n anymore.
  ushort_t* Wh_n = (ushort_t*)d_out;

  hipMemsetAsync(zstart, 0, zbytes, stream);

  k_count<<<cdiv(NI, 256), 256, 0, stream>>>(node_idx, hedge_idx, NI, cnt_v, cnt_e,
                                             rank_v, rank_e);

  int nbe = cdiv(NE, 1024), nbv = cdiv(NV, 1024);
  k_scan_partial<<<nbe, 256, 0, stream>>>(cnt_e, NE, bsum_e);
  k_scan_bsums<<<1, 256, 0, stream>>>(bsum_e, nbe);
  k_scan_final<<<nbe, 256, 0, stream>>>(cnt_e, NE, bsum_e, off_e);
  k_scan_partial<<<nbv, 256, 0, stream>>>(cnt_v, NV, bsum_v);
  k_scan_bsums<<<1, 256, 0, stream>>>(bsum_v, nbv);
  k_scan_final<<<nbv, 256, 0, stream>>>(cnt_v, NV, bsum_v, off_v);

  k_fill2<<<cdiv(NI, 256), 256, 0, stream>>>(node_idx, hedge_idx, rank_v, rank_e,
                                             NI, off_v, off_e, vlist_e, elist_v);

  k_wmerge<<<D, D, 0, stream>>>(W1, Wve, b1, bve, Wc, bc);

  int g1 = cdiv(NV, 32); if (g1 > 512) g1 = 512;
  k_gemm<true><<<g1, 256, 0, stream>>>(vfeat, Wc, bc, Wh_n, NV);

  k_scatter<<<cdiv(NE * 64, 256), 256, 0, stream>>>(Wh_n, off_e, cnt_e, elist_v,
                                                    v_reg_weight, e_reg_sum, feat_e, NE);

  int g2 = cdiv(NE, 32); if (g2 > 512) g2 = 512;
  k_gemm<true><<<g2, 256, 0, stream>>>(feat_e, Wev, bev, Wh_e, NE);

  k_scatter<<<cdiv(NV * 64, 256), 256, 0, stream>>>(Wh_e, off_v, cnt_v, vlist_e,
                                                    e_reg_weight, v_reg_sum, (float*)d_out, NV);
}

// Round 3
// 235.741 us; speedup vs baseline: 1.5239x; 1.2124x over previous
//
#include <hip/hip_runtime.h>

#define D 128

typedef unsigned short ushort_t;
typedef short short8 __attribute__((ext_vector_type(8)));
typedef ushort_t ushort8v __attribute__((ext_vector_type(8)));
typedef float f32x4 __attribute__((ext_vector_type(4)));

static __device__ __forceinline__ unsigned short f2bf(float f){
  unsigned int b = __float_as_uint(f);
  unsigned int r = (b + 0x7FFFu + ((b >> 16) & 1u)) >> 16;
  return (unsigned short)r;
}
static __device__ __forceinline__ float bf2f(unsigned short u){
  return __uint_as_float(((unsigned int)u) << 16);
}

// ---------------- CSR build ----------------

__global__ void k_count(const int* __restrict__ node_idx, const int* __restrict__ hedge_idx,
                        int ni, int* __restrict__ cnt_v, int* __restrict__ cnt_e,
                        int* __restrict__ rank_v, int* __restrict__ rank_e){
  int i = blockIdx.x * 256 + threadIdx.x;
  if (i < ni){
    rank_v[i] = atomicAdd(&cnt_v[node_idx[i]], 1);
    rank_e[i] = atomicAdd(&cnt_e[hedge_idx[i]], 1);
  }
}

__global__ void k_scan_partial(const int* __restrict__ cnt, int n, int* __restrict__ bsum){
  __shared__ int s[256];
  int b = blockIdx.x, t = threadIdx.x;
  int base = b * 1024;
  int acc = 0;
  for (int j = t; j < 1024; j += 256){
    int idx = base + j;
    if (idx < n) acc += cnt[idx];
  }
  s[t] = acc; __syncthreads();
  for (int o = 128; o > 0; o >>= 1){
    if (t < o) s[t] += s[t + o];
    __syncthreads();
  }
  if (t == 0) bsum[b] = s[0];
}

__global__ void k_scan_bsums(int* __restrict__ bsum, int nb){
  __shared__ int s[256];
  int t = threadIdx.x;
  int runbase = 0;
  for (int base = 0; base < nb; base += 256){
    int v = (base + t < nb) ? bsum[base + t] : 0;
    s[t] = v;
    __syncthreads();
    for (int o = 1; o < 256; o <<= 1){
      int x = (t >= o) ? s[t - o] : 0;
      __syncthreads();
      s[t] += x;
      __syncthreads();
    }
    int total = s[255];
    if (base + t < nb) bsum[base + t] = runbase + (s[t] - v);  // exclusive
    __syncthreads();
    runbase += total;
  }
}

__global__ void k_scan_final(const int* __restrict__ cnt, int n,
                             const int* __restrict__ bsum, int* __restrict__ off){
  __shared__ int s[256];
  int b = blockIdx.x, t = threadIdx.x;
  int base = b * 1024 + t * 4;
  int v0 = (base + 0 < n) ? cnt[base + 0] : 0;
  int v1 = (base + 1 < n) ? cnt[base + 1] : 0;
  int v2 = (base + 2 < n) ? cnt[base + 2] : 0;
  int v3 = (base + 3 < n) ? cnt[base + 3] : 0;
  int lsum = v0 + v1 + v2 + v3;
  s[t] = lsum; __syncthreads();
  for (int o = 1; o < 256; o <<= 1){
    int x = (t >= o) ? s[t - o] : 0;
    __syncthreads();
    s[t] += x;
    __syncthreads();
  }
  int excl = s[t] - lsum + bsum[b];
  if (base + 0 < n) off[base + 0] = excl;
  if (base + 1 < n) off[base + 1] = excl + v0;
  if (base + 2 < n) off[base + 2] = excl + v0 + v1;
  if (base + 3 < n) off[base + 3] = excl + v0 + v1 + v2;
}

__global__ void k_fill2(const int* __restrict__ node_idx, const int* __restrict__ hedge_idx,
                        const int* __restrict__ rank_v, const int* __restrict__ rank_e,
                        int ni, const int* __restrict__ off_v, const int* __restrict__ off_e,
                        int* __restrict__ vlist_e, int* __restrict__ elist_v){
  int i = blockIdx.x * 256 + threadIdx.x;
  if (i < ni){
    int v = node_idx[i];
    int e = hedge_idx[i];
    int pe = off_e[e] + rank_e[i];
    __builtin_nontemporal_store(v, &elist_v[pe]);
    int pv = off_v[v] + rank_v[i];
    __builtin_nontemporal_store(e, &vlist_e[pv]);
  }
}

// ---------------- weight prep ----------------
// Wc(bf16) = Wve @ W1, bc = Wve@b1 + bve

__global__ void k_wmerge(const float* __restrict__ W1, const float* __restrict__ Wve,
                         const float* __restrict__ b1, const float* __restrict__ bve,
                         ushort_t* __restrict__ Wc, float* __restrict__ bc){
  int r = blockIdx.x;   // 0..127
  int c = threadIdx.x;  // 0..127
  float acc = 0.f;
  for (int k = 0; k < D; ++k)
    acc += Wve[r * D + k] * W1[k * D + c];
  Wc[r * D + c] = f2bf(acc);
  if (c == 0){
    float s = 0.f;
    for (int k = 0; k < D; ++k) s += Wve[r * D + k] * b1[k];
    bc[r] = s + bve[r];
  }
}

__global__ void k_wconv(const float* __restrict__ W, ushort_t* __restrict__ Wb){
  int i = blockIdx.x * 256 + threadIdx.x;
  if (i < D * D) Wb[i] = f2bf(W[i]);
}

// ---------------- MFMA GEMM: out(bf16)[M x 128] = A(f32)[M x 128] @ Wb(bf16).T + bias ----
// Wb is [128 x 128] bf16 row-major, Wb[c][k]. Tile: 64 rows x 128 cols, 4 waves.
// Wave w owns rows w*16..w*16+15; 8 n-fragments; K via 4 mfma_16x16x32 chunks.
// B fragments live in registers (preloaded once); A staged to LDS as bf16,
// XOR-swizzled (ushort col8 ^ ((row&7)<<3)) for bank-balanced ds_read_b128.

__global__ __launch_bounds__(256, 2)
void k_gemm_mfma(const float* __restrict__ A, const ushort_t* __restrict__ Wb,
                 const float* __restrict__ bias, ushort_t* __restrict__ out, int M){
  __shared__ ushort_t Al[64 * D];   // 16 KB

  const int t = threadIdx.x;
  const int w = t >> 6;
  const int l = t & 63;
  const int l15 = l & 15;
  const int lh = l >> 4;            // 0..3

  // Preload B fragments: breg[kc][n0]; lane l holds Wb[n0*16+l15][kc*32+lh*8 .. +7].
  // A-frag uses the identical (lh,j)->k mapping, so any HW k-permutation cancels.
  short8 breg[4][8];
#pragma unroll
  for (int kc = 0; kc < 4; ++kc)
#pragma unroll
    for (int n0 = 0; n0 < 8; ++n0)
      breg[kc][n0] = *(const short8*)&Wb[(n0 * 16 + l15) * D + kc * 32 + lh * 8];

  float bias_r[8];
#pragma unroll
  for (int n0 = 0; n0 < 8; ++n0) bias_r[n0] = bias[n0 * 16 + l15];

  const int r_st = t >> 2;          // staging row 0..63
  const int q_st = t & 3;           // k-quarter 0..3
  const int ntile = (M + 63) >> 6;

  for (int tile = blockIdx.x; tile < ntile; tile += gridDim.x){
    const int row0 = tile << 6;
    __syncthreads();                // previous-iter readers done before overwrite
    {
      int r = row0 + r_st;
      float4 v[8];
      if (r < M){
        const float4* src = (const float4*)&A[(size_t)r * D + q_st * 32];
#pragma unroll
        for (int i = 0; i < 8; ++i) v[i] = src[i];
      } else {
#pragma unroll
        for (int i = 0; i < 8; ++i){ v[i].x = v[i].y = v[i].z = v[i].w = 0.f; }
      }
#pragma unroll
      for (int c = 0; c < 4; ++c){
        ushort8v h;
        h[0] = f2bf(v[2*c].x);   h[1] = f2bf(v[2*c].y);
        h[2] = f2bf(v[2*c].z);   h[3] = f2bf(v[2*c].w);
        h[4] = f2bf(v[2*c+1].x); h[5] = f2bf(v[2*c+1].y);
        h[6] = f2bf(v[2*c+1].z); h[7] = f2bf(v[2*c+1].w);
        int col = q_st * 32 + c * 8;
        int swz = col ^ ((r_st & 7) << 3);
        *(ushort8v*)&Al[r_st * D + swz] = h;
      }
    }
    __syncthreads();

    f32x4 acc[8];
#pragma unroll
    for (int n0 = 0; n0 < 8; ++n0) acc[n0] = (f32x4){0.f, 0.f, 0.f, 0.f};

#pragma unroll
    for (int kc = 0; kc < 4; ++kc){
      const int arow = w * 16 + l15;
      const int acol = (kc * 32 + lh * 8) ^ ((l15 & 7) << 3);
      short8 a = *(const short8*)&Al[arow * D + acol];
#pragma unroll
      for (int n0 = 0; n0 < 8; ++n0)
        acc[n0] = __builtin_amdgcn_mfma_f32_16x16x32_bf16(a, breg[kc][n0], acc[n0], 0, 0, 0);
    }

    // C/D layout (verified m89): col = lane&15, row = (lane>>4)*4 + reg
    const int rbase = row0 + w * 16 + lh * 4;
#pragma unroll
    for (int n0 = 0; n0 < 8; ++n0){
      const int colo = n0 * 16 + l15;
#pragma unroll
      for (int rg = 0; rg < 4; ++rg){
        int row = rbase + rg;
        if (row < M) out[(size_t)row * D + colo] = f2bf(acc[n0][rg] + bias_r[n0]);
      }
    }
  }
}

// ---------------- weighted segment gather-sum (bf16 source rows) ----------------

__global__ void k_scatter(const ushort_t* __restrict__ src,
                          const int* __restrict__ off, const int* __restrict__ cnt,
                          const int* __restrict__ list,
                          const float* __restrict__ wnum, const float* __restrict__ dsum,
                          float* __restrict__ dst, int nseg){
  int gw = (blockIdx.x * 256 + threadIdx.x) >> 6;
  if (gw >= nseg) return;
  int lane = threadIdx.x & 63;
  int s = __builtin_amdgcn_readfirstlane(off[gw]);
  int n = __builtin_amdgcn_readfirstlane(cnt[gw]);
  float inv = 1.0f / dsum[gw];
  float ax = 0.f, ay = 0.f;
  int j = 0;
  for (; j + 2 <= n; j += 2){
    int r0 = __builtin_amdgcn_readfirstlane(list[s + j]);
    int r1 = __builtin_amdgcn_readfirstlane(list[s + j + 1]);
    float w0 = wnum[r0] * inv;
    float w1 = wnum[r1] * inv;
    ushort2 x0 = *(const ushort2*)&src[(size_t)r0 * D + lane * 2];
    ushort2 x1 = *(const ushort2*)&src[(size_t)r1 * D + lane * 2];
    ax += w0 * bf2f(x0.x); ay += w0 * bf2f(x0.y);
    ax += w1 * bf2f(x1.x); ay += w1 * bf2f(x1.y);
  }
  if (j < n){
    int r0 = __builtin_amdgcn_readfirstlane(list[s + j]);
    float w0 = wnum[r0] * inv;
    ushort2 x0 = *(const ushort2*)&src[(size_t)r0 * D + lane * 2];
    ax += w0 * bf2f(x0.x); ay += w0 * bf2f(x0.y);
  }
  float2 o; o.x = ax; o.y = ay;
  *(float2*)&dst[(size_t)gw * D + lane * 2] = o;
}

// ---------------- host ----------------

static inline int cdiv(int a, int b){ return (a + b - 1) / b; }

extern "C" void kernel_launch(void* const* d_in, const int* in_sizes, int n_in,
                              void* d_out, int out_size, void* d_ws, size_t ws_size,
                              hipStream_t stream){
  const float* vfeat        = (const float*)d_in[0];
  const float* v_reg_weight = (const float*)d_in[2];
  const float* v_reg_sum    = (const float*)d_in[3];
  const float* e_reg_weight = (const float*)d_in[4];
  const float* e_reg_sum    = (const float*)d_in[5];
  const int*   node_idx     = (const int*)d_in[6];
  const int*   hedge_idx    = (const int*)d_in[7];
  const float* W1  = (const float*)d_in[8];
  const float* b1  = (const float*)d_in[9];
  const float* Wve = (const float*)d_in[10];
  const float* bve = (const float*)d_in[11];
  const float* Wev = (const float*)d_in[12];
  const float* bev = (const float*)d_in[13];

  const int NV = in_sizes[2];
  const int NE = in_sizes[4];
  const int NI = in_sizes[6];

  char* p = (char*)d_ws;
  auto alloc = [&](size_t nbytes) -> void* {
    void* q = (void*)p;
    p += (nbytes + 255) & ~(size_t)255;
    return q;
  };

  char* zstart = p;
  int* cnt_v = (int*)alloc((size_t)NV * 4);
  int* cnt_e = (int*)alloc((size_t)NE * 4);
  size_t zbytes = (size_t)(p - zstart);

  int* off_v  = (int*)alloc((size_t)NV * 4);
  int* off_e  = (int*)alloc((size_t)NE * 4);
  int* bsum_v = (int*)alloc(1024 * 4);
  int* bsum_e = (int*)alloc(1024 * 4);
  int* rank_v = (int*)alloc((size_t)NI * 4);
  int* rank_e = (int*)alloc((size_t)NI * 4);
  int* vlist_e = (int*)alloc((size_t)NI * 4);   // per vertex-slot: edge id
  int* elist_v = (int*)alloc((size_t)NI * 4);   // per edge-slot: vertex id
  ushort_t* Wc   = (ushort_t*)alloc((size_t)D * D * 2);
  ushort_t* Wevb = (ushort_t*)alloc((size_t)D * D * 2);
  float* bc     = (float*)alloc((size_t)D * 4);
  float* feat_e = (float*)alloc((size_t)NE * D * 4);
  ushort_t* Wh_e = (ushort_t*)alloc((size_t)NE * D * 2);

  // Wh_n (bf16) lives in d_out's storage; fully overwritten by final scatter.
  ushort_t* Wh_n = (ushort_t*)d_out;

  hipMemsetAsync(zstart, 0, zbytes, stream);

  k_count<<<cdiv(NI, 256), 256, 0, stream>>>(node_idx, hedge_idx, NI, cnt_v, cnt_e,
                                             rank_v, rank_e);

  int nbe = cdiv(NE, 1024), nbv = cdiv(NV, 1024);
  k_scan_partial<<<nbe, 256, 0, stream>>>(cnt_e, NE, bsum_e);
  k_scan_bsums<<<1, 256, 0, stream>>>(bsum_e, nbe);
  k_scan_final<<<nbe, 256, 0, stream>>>(cnt_e, NE, bsum_e, off_e);
  k_scan_partial<<<nbv, 256, 0, stream>>>(cnt_v, NV, bsum_v);
  k_scan_bsums<<<1, 256, 0, stream>>>(bsum_v, nbv);
  k_scan_final<<<nbv, 256, 0, stream>>>(cnt_v, NV, bsum_v, off_v);

  k_fill2<<<cdiv(NI, 256), 256, 0, stream>>>(node_idx, hedge_idx, rank_v, rank_e,
                                             NI, off_v, off_e, vlist_e, elist_v);

  k_wmerge<<<D, D, 0, stream>>>(W1, Wve, b1, bve, Wc, bc);
  k_wconv<<<cdiv(D * D, 256), 256, 0, stream>>>(Wev, Wevb);

  int g1 = cdiv(NV, 64); if (g1 > 512) g1 = 512;
  k_gemm_mfma<<<g1, 256, 0, stream>>>(vfeat, Wc, bc, Wh_n, NV);

  k_scatter<<<cdiv(NE * 64, 256), 256, 0, stream>>>(Wh_n, off_e, cnt_e, elist_v,
                                                    v_reg_weight, e_reg_sum, feat_e, NE);

  int g2 = cdiv(NE, 64); if (g2 > 512) g2 = 512;
  k_gemm_mfma<<<g2, 256, 0, stream>>>(feat_e, Wevb, bev, Wh_e, NE);

  k_scatter<<<cdiv(NV * 64, 256), 256, 0, stream>>>(Wh_e, off_v, cnt_v, vlist_e,
                                                    e_reg_weight, v_reg_sum, (float*)d_out, NV);
}

// Round 4
// 218.972 us; speedup vs baseline: 1.6406x; 1.0766x over previous
//
#include <hip/hip_runtime.h>

#define D 128
#define GEMM_BLOCKS 512

typedef unsigned short ushort_t;
typedef short short8 __attribute__((ext_vector_type(8)));
typedef ushort_t ushort8v __attribute__((ext_vector_type(8)));
typedef float f32x4 __attribute__((ext_vector_type(4)));

static __device__ __forceinline__ unsigned short f2bf(float f){
  unsigned int b = __float_as_uint(f);
  unsigned int r = (b + 0x7FFFu + ((b >> 16) & 1u)) >> 16;
  return (unsigned short)r;
}
static __device__ __forceinline__ float bf2f(unsigned short u){
  return __uint_as_float(((unsigned int)u) << 16);
}

// ---------------- U1: count (atomic ranks) UNION wmerge ----------------
// blocks [0,128): wmerge row r = blockIdx; blocks [128, ...): count chunk.

__global__ void k_u1(const int* __restrict__ node_idx, const int* __restrict__ hedge_idx,
                     int ni, int* __restrict__ cnt_v, int* __restrict__ cnt_e,
                     int* __restrict__ rank_v, int* __restrict__ rank_e,
                     const float* __restrict__ W1, const float* __restrict__ Wve,
                     const float* __restrict__ b1, const float* __restrict__ bve,
                     ushort_t* __restrict__ Wc, float* __restrict__ bc){
  int t = threadIdx.x;
  if (blockIdx.x < 128){
    int r = blockIdx.x;
    if (t < D){
      float acc = 0.f;
      for (int k = 0; k < D; ++k)
        acc += Wve[r * D + k] * W1[k * D + t];
      Wc[r * D + t] = f2bf(acc);
      if (t == 0){
        float s = 0.f;
        for (int k = 0; k < D; ++k) s += Wve[r * D + k] * b1[k];
        bc[r] = s + bve[r];
      }
    }
  } else {
    int i = (blockIdx.x - 128) * 256 + t;
    if (i < ni){
      rank_v[i] = atomicAdd(&cnt_v[node_idx[i]], 1);
      rank_e[i] = atomicAdd(&cnt_e[hedge_idx[i]], 1);
    }
  }
}

// ---------------- fused scans (e then v) ----------------

__device__ __forceinline__ void scan_partial_body(const int* cnt, int n, int* bsum, int b){
  __shared__ int s[256];
  int t = threadIdx.x;
  int base = b * 1024;
  int acc = 0;
  for (int j = t; j < 1024; j += 256){
    int idx = base + j;
    if (idx < n) acc += cnt[idx];
  }
  s[t] = acc; __syncthreads();
  for (int o = 128; o > 0; o >>= 1){
    if (t < o) s[t] += s[t + o];
    __syncthreads();
  }
  if (t == 0) bsum[b] = s[0];
}

__global__ void k_scan_partial2(const int* __restrict__ cnt_e, int ne, int* __restrict__ bsum_e,
                                const int* __restrict__ cnt_v, int nv, int* __restrict__ bsum_v,
                                int nbe){
  if ((int)blockIdx.x < nbe) scan_partial_body(cnt_e, ne, bsum_e, blockIdx.x);
  else                       scan_partial_body(cnt_v, nv, bsum_v, blockIdx.x - nbe);
}

__device__ __forceinline__ void scan_bsums_body(int* bsum, int nb){
  __shared__ int s[256];
  int t = threadIdx.x;
  int runbase = 0;
  for (int base = 0; base < nb; base += 256){
    int v = (base + t < nb) ? bsum[base + t] : 0;
    s[t] = v;
    __syncthreads();
    for (int o = 1; o < 256; o <<= 1){
      int x = (t >= o) ? s[t - o] : 0;
      __syncthreads();
      s[t] += x;
      __syncthreads();
    }
    int total = s[255];
    if (base + t < nb) bsum[base + t] = runbase + (s[t] - v);  // exclusive
    __syncthreads();
    runbase += total;
  }
}

__global__ void k_scan_bsums2(int* __restrict__ bsum_e, int nbe,
                              int* __restrict__ bsum_v, int nbv){
  if (blockIdx.x == 0) scan_bsums_body(bsum_e, nbe);
  else                 scan_bsums_body(bsum_v, nbv);
}

__device__ __forceinline__ void scan_final_body(const int* cnt, int n, const int* bsum,
                                                int* off, int b){
  __shared__ int s[256];
  int t = threadIdx.x;
  int base = b * 1024 + t * 4;
  int v0 = (base + 0 < n) ? cnt[base + 0] : 0;
  int v1 = (base + 1 < n) ? cnt[base + 1] : 0;
  int v2 = (base + 2 < n) ? cnt[base + 2] : 0;
  int v3 = (base + 3 < n) ? cnt[base + 3] : 0;
  int lsum = v0 + v1 + v2 + v3;
  s[t] = lsum; __syncthreads();
  for (int o = 1; o < 256; o <<= 1){
    int x = (t >= o) ? s[t - o] : 0;
    __syncthreads();
    s[t] += x;
    __syncthreads();
  }
  int excl = s[t] - lsum + bsum[b];
  if (base + 0 < n) off[base + 0] = excl;
  if (base + 1 < n) off[base + 1] = excl + v0;
  if (base + 2 < n) off[base + 2] = excl + v0 + v1;
  if (base + 3 < n) off[base + 3] = excl + v0 + v1 + v2;
}

__global__ void k_scan_final2(const int* __restrict__ cnt_e, int ne, const int* __restrict__ bsum_e,
                              int* __restrict__ off_e,
                              const int* __restrict__ cnt_v, int nv, const int* __restrict__ bsum_v,
                              int* __restrict__ off_v, int nbe){
  if ((int)blockIdx.x < nbe) scan_final_body(cnt_e, ne, bsum_e, off_e, blockIdx.x);
  else                       scan_final_body(cnt_v, nv, bsum_v, off_v, blockIdx.x - nbe);
}

// ---------------- MFMA GEMM body (shared by U2 and standalone) ----------------
// out(bf16)[M x 128] = A[M x 128] @ Wb(bf16).T + bias. A is f32 or bf16.
// Tile: 64 rows x 128 cols, 4 waves; B fragments in registers; A-tile in LDS,
// XOR-swizzled (ushort col8 ^ ((row&7)<<3)).

template<bool BF16IN>
__device__ __forceinline__ void gemm_body(const void* __restrict__ A_,
                                          const ushort_t* __restrict__ Wb,
                                          const float* __restrict__ bias,
                                          ushort_t* __restrict__ out, int M,
                                          int bid, int nblocks, ushort_t* Al){
  const int t = threadIdx.x;
  const int w = t >> 6;
  const int l = t & 63;
  const int l15 = l & 15;
  const int lh = l >> 4;            // 0..3

  short8 breg[4][8];
#pragma unroll
  for (int kc = 0; kc < 4; ++kc)
#pragma unroll
    for (int n0 = 0; n0 < 8; ++n0)
      breg[kc][n0] = *(const short8*)&Wb[(n0 * 16 + l15) * D + kc * 32 + lh * 8];

  float bias_r[8];
#pragma unroll
  for (int n0 = 0; n0 < 8; ++n0) bias_r[n0] = bias[n0 * 16 + l15];

  const int r_st = t >> 2;          // staging row 0..63
  const int q_st = t & 3;           // k-quarter (32 cols)
  const int ntile = (M + 63) >> 6;

  for (int tile = bid; tile < ntile; tile += nblocks){
    const int row0 = tile << 6;
    __syncthreads();
    {
      int r = row0 + r_st;
      ushort8v h[4];
      if (r < M){
        if (BF16IN){
          const ushort8v* src = (const ushort8v*)((const ushort_t*)A_ + (size_t)r * D + q_st * 32);
#pragma unroll
          for (int c = 0; c < 4; ++c) h[c] = src[c];
        } else {
          const float4* src = (const float4*)((const float*)A_ + (size_t)r * D + q_st * 32);
          float4 v[8];
#pragma unroll
          for (int i = 0; i < 8; ++i) v[i] = src[i];
#pragma unroll
          for (int c = 0; c < 4; ++c){
            h[c][0] = f2bf(v[2*c].x);   h[c][1] = f2bf(v[2*c].y);
            h[c][2] = f2bf(v[2*c].z);   h[c][3] = f2bf(v[2*c].w);
            h[c][4] = f2bf(v[2*c+1].x); h[c][5] = f2bf(v[2*c+1].y);
            h[c][6] = f2bf(v[2*c+1].z); h[c][7] = f2bf(v[2*c+1].w);
          }
        }
      } else {
#pragma unroll
        for (int c = 0; c < 4; ++c) h[c] = (ushort8v){0,0,0,0,0,0,0,0};
      }
#pragma unroll
      for (int c = 0; c < 4; ++c){
        int col = q_st * 32 + c * 8;
        int swz = col ^ ((r_st & 7) << 3);
        *(ushort8v*)&Al[r_st * D + swz] = h[c];
      }
    }
    __syncthreads();

    f32x4 acc[8];
#pragma unroll
    for (int n0 = 0; n0 < 8; ++n0) acc[n0] = (f32x4){0.f, 0.f, 0.f, 0.f};

#pragma unroll
    for (int kc = 0; kc < 4; ++kc){
      const int arow = w * 16 + l15;
      const int acol = (kc * 32 + lh * 8) ^ ((l15 & 7) << 3);
      short8 a = *(const short8*)&Al[arow * D + acol];
#pragma unroll
      for (int n0 = 0; n0 < 8; ++n0)
        acc[n0] = __builtin_amdgcn_mfma_f32_16x16x32_bf16(a, breg[kc][n0], acc[n0], 0, 0, 0);
    }

    // C/D layout: col = lane&15, row = (lane>>4)*4 + reg
    const int rbase = row0 + w * 16 + lh * 4;
#pragma unroll
    for (int n0 = 0; n0 < 8; ++n0){
      const int colo = n0 * 16 + l15;
#pragma unroll
      for (int rg = 0; rg < 4; ++rg){
        int row = rbase + rg;
        if (row < M) out[(size_t)row * D + colo] = f2bf(acc[n0][rg] + bias_r[n0]);
      }
    }
  }
}

template<bool BF16IN>
__global__ __launch_bounds__(256, 2)
void k_gemm(const void* __restrict__ A_, const ushort_t* __restrict__ Wb,
            const float* __restrict__ bias, ushort_t* __restrict__ out, int M){
  __shared__ ushort_t Al[64 * D];
  gemm_body<BF16IN>(A_, Wb, bias, out, M, blockIdx.x, gridDim.x, Al);
}

// ---------------- U2: gemm1 (f32 in) UNION CSR fill ----------------

__global__ __launch_bounds__(256, 2)
void k_u2(const float* __restrict__ A, const ushort_t* __restrict__ Wb,
          const float* __restrict__ bias, ushort_t* __restrict__ out, int M,
          const int* __restrict__ node_idx, const int* __restrict__ hedge_idx,
          const int* __restrict__ rank_v, const int* __restrict__ rank_e, int ni,
          const int* __restrict__ off_v, const int* __restrict__ off_e,
          int* __restrict__ vlist_e, int* __restrict__ elist_v){
  __shared__ ushort_t Al[64 * D];
  if (blockIdx.x < GEMM_BLOCKS){
    gemm_body<false>(A, Wb, bias, out, M, blockIdx.x, GEMM_BLOCKS, Al);
  } else {
    int i = (blockIdx.x - GEMM_BLOCKS) * 256 + threadIdx.x;
    if (i < ni){
      int v = node_idx[i];
      int e = hedge_idx[i];
      int pe = off_e[e] + rank_e[i];
      __builtin_nontemporal_store(v, &elist_v[pe]);
      int pv = off_v[v] + rank_v[i];
      __builtin_nontemporal_store(e, &vlist_e[pv]);
    }
  }
}

// ---------------- weighted segment gather-sum, 4 items/iter ----------------
// Wave per segment; lane-group g (16 lanes) handles item j+g; each lane loads
// 16B (8 bf16 cols); cross-group fold via shfl_xor(16/32).

template<bool BF16OUT>
__global__ void k_scatter4(const ushort_t* __restrict__ src,
                           const int* __restrict__ off, const int* __restrict__ cnt,
                           const int* __restrict__ list,
                           const float* __restrict__ wnum, const float* __restrict__ dsum,
                           void* __restrict__ dst_, int nseg){
  int gw = (blockIdx.x * 256 + threadIdx.x) >> 6;
  if (gw >= nseg) return;
  int lane = threadIdx.x & 63;
  int l15 = lane & 15;
  int g = lane >> 4;
  int s = __builtin_amdgcn_readfirstlane(off[gw]);
  int n = __builtin_amdgcn_readfirstlane(cnt[gw]);
  float inv = 1.0f / dsum[gw];

  float acc[8];
#pragma unroll
  for (int c = 0; c < 8; ++c) acc[c] = 0.f;

  for (int j = 0; j < n; j += 4){
    int jj = j + g;
    bool ok = jj < n;
    int r = list[s + (ok ? jj : 0)];
    float wt = ok ? wnum[r] * inv : 0.f;
    ushort8v x = *(const ushort8v*)&src[(size_t)r * D + l15 * 8];
#pragma unroll
    for (int c = 0; c < 8; ++c) acc[c] += wt * bf2f(x[c]);
  }

#pragma unroll
  for (int c = 0; c < 8; ++c){
    acc[c] += __shfl_xor(acc[c], 16);
    acc[c] += __shfl_xor(acc[c], 32);
  }

  if (g == 0){
    if (BF16OUT){
      ushort8v h;
#pragma unroll
      for (int c = 0; c < 8; ++c) h[c] = f2bf(acc[c]);
      *(ushort8v*)((ushort_t*)dst_ + (size_t)gw * D + l15 * 8) = h;
    } else {
      float* dp = (float*)dst_ + (size_t)gw * D + l15 * 8;
      float4 o0, o1;
      o0.x = acc[0]; o0.y = acc[1]; o0.z = acc[2]; o0.w = acc[3];
      o1.x = acc[4]; o1.y = acc[5]; o1.z = acc[6]; o1.w = acc[7];
      *(float4*)dp = o0;
      *(float4*)(dp + 4) = o1;
    }
  }
}

// ---------------- weight convert ----------------

__global__ void k_wconv(const float* __restrict__ W, ushort_t* __restrict__ Wb){
  int i = blockIdx.x * 256 + threadIdx.x;
  if (i < D * D) Wb[i] = f2bf(W[i]);
}

// ---------------- host ----------------

static inline int cdiv(int a, int b){ return (a + b - 1) / b; }

extern "C" void kernel_launch(void* const* d_in, const int* in_sizes, int n_in,
                              void* d_out, int out_size, void* d_ws, size_t ws_size,
                              hipStream_t stream){
  const float* vfeat        = (const float*)d_in[0];
  const float* v_reg_weight = (const float*)d_in[2];
  const float* v_reg_sum    = (const float*)d_in[3];
  const float* e_reg_weight = (const float*)d_in[4];
  const float* e_reg_sum    = (const float*)d_in[5];
  const int*   node_idx     = (const int*)d_in[6];
  const int*   hedge_idx    = (const int*)d_in[7];
  const float* W1  = (const float*)d_in[8];
  const float* b1  = (const float*)d_in[9];
  const float* Wve = (const float*)d_in[10];
  const float* bve = (const float*)d_in[11];
  const float* Wev = (const float*)d_in[12];
  const float* bev = (const float*)d_in[13];

  const int NV = in_sizes[2];
  const int NE = in_sizes[4];
  const int NI = in_sizes[6];

  char* p = (char*)d_ws;
  auto alloc = [&](size_t nbytes) -> void* {
    void* q = (void*)p;
    p += (nbytes + 255) & ~(size_t)255;
    return q;
  };

  char* zstart = p;
  int* cnt_v = (int*)alloc((size_t)NV * 4);
  int* cnt_e = (int*)alloc((size_t)NE * 4);
  size_t zbytes = (size_t)(p - zstart);

  int* off_v  = (int*)alloc((size_t)NV * 4);
  int* off_e  = (int*)alloc((size_t)NE * 4);
  int* bsum_e = (int*)alloc(1024 * 4);
  int* bsum_v = (int*)alloc(1024 * 4);
  int* rank_v = (int*)alloc((size_t)NI * 4);
  int* rank_e = (int*)alloc((size_t)NI * 4);
  int* vlist_e = (int*)alloc((size_t)NI * 4);   // per vertex-slot: edge id
  int* elist_v = (int*)alloc((size_t)NI * 4);   // per edge-slot: vertex id
  ushort_t* Wc   = (ushort_t*)alloc((size_t)D * D * 2);
  ushort_t* Wevb = (ushort_t*)alloc((size_t)D * D * 2);
  float* bc      = (float*)alloc((size_t)D * 4);
  ushort_t* feat_e = (ushort_t*)alloc((size_t)NE * D * 2);
  ushort_t* Wh_e   = (ushort_t*)alloc((size_t)NE * D * 2);

  // Wh_n (bf16) lives in d_out's storage; fully overwritten by final scatter.
  ushort_t* Wh_n = (ushort_t*)d_out;

  hipMemsetAsync(zstart, 0, zbytes, stream);

  // U1: wmerge (blocks 0..127) + count-with-ranks (atomic-bound, ~53us)
  k_u1<<<128 + cdiv(NI, 256), 256, 0, stream>>>(node_idx, hedge_idx, NI, cnt_v, cnt_e,
                                                rank_v, rank_e,
                                                W1, Wve, b1, bve, Wc, bc);
  // Wev bf16 convert (tiny, independent; rides behind U1)
  k_wconv<<<cdiv(D * D, 256), 256, 0, stream>>>(Wev, Wevb);

  int nbe = cdiv(NE, 1024), nbv = cdiv(NV, 1024);
  k_scan_partial2<<<nbe + nbv, 256, 0, stream>>>(cnt_e, NE, bsum_e, cnt_v, NV, bsum_v, nbe);
  k_scan_bsums2<<<2, 256, 0, stream>>>(bsum_e, nbe, bsum_v, nbv);
  k_scan_final2<<<nbe + nbv, 256, 0, stream>>>(cnt_e, NE, bsum_e, off_e,
                                               cnt_v, NV, bsum_v, off_v, nbe);

  // U2: gemm1 (blocks 0..511, vfeat f32 -> Wh_n bf16) + CSR fill
  k_u2<<<GEMM_BLOCKS + cdiv(NI, 256), 256, 0, stream>>>(vfeat, Wc, bc, Wh_n, NV,
                                                        node_idx, hedge_idx, rank_v, rank_e, NI,
                                                        off_v, off_e, vlist_e, elist_v);

  // node -> hyperedge: feat_e (bf16)
  k_scatter4<true><<<cdiv(NE * 64, 256), 256, 0, stream>>>(Wh_n, off_e, cnt_e, elist_v,
                                                           v_reg_weight, e_reg_sum,
                                                           feat_e, NE);

  // edge linear: Wh_e (bf16) = feat_e @ Wev.T + bev
  int g2 = cdiv(NE, 64); if (g2 > 512) g2 = 512;
  k_gemm<true><<<g2, 256, 0, stream>>>(feat_e, Wevb, bev, Wh_e, NE);

  // hyperedge -> node: d_out (f32)
  k_scatter4<false><<<cdiv(NV * 64, 256), 256, 0, stream>>>(Wh_e, off_v, cnt_v, vlist_e,
                                                            e_reg_weight, v_reg_sum,
                                                            d_out, NV);
}